// Round 1
// baseline (140.446 us; speedup 1.0000x reference)
//
#include <hip/hip_runtime.h>
#include <math.h>

// SNN forward: ConstantCurrentLIFEncoder -> LIFCell -> LILinearCell, T=32.
// One block per batch item (B=4096), 256 threads, 4 neurons/thread (784 total).
// Spike path (matvec + reduction) is skipped entirely via __syncthreads_or
// when no neuron in the block spiked this step (always true for U[0,1) input,
// but correctness does not depend on that).

#define T_STEPS 32
#define N_IN 784
#define N_OUT 10
#define NK 4            // neurons per thread (256*4 = 1024 >= 784)

__global__ __launch_bounds__(256) void snn_fused_kernel(
    const float* __restrict__ image,   // [B, 784]
    const float* __restrict__ W,       // [10, 784]
    float* __restrict__ out)           // [B, 10]
{
    constexpr float DT_TMI  = 0.1f;    // DT * TAU_MEM_INV
    constexpr float DEC_SYN = 0.8f;    // 1 - DT * TAU_SYN_INV
    constexpr float V_TH    = 1.0f;

    const int b   = blockIdx.x;
    const int tid = threadIdx.x;
    const float* __restrict__ x_row = image + (size_t)b * N_IN;

    // per-thread neuron state in registers
    float xk[NK], v_enc[NK], v0[NK], i0[NK];
    int   jn[NK];
#pragma unroll
    for (int k = 0; k < NK; ++k) {
        int j = tid + 256 * k;
        jn[k]    = j;
        xk[k]    = (j < N_IN) ? x_row[j] : 0.0f;  // x=0 => lane never spikes
        v_enc[k] = 0.0f;
        v0[k]    = 0.0f;
        i0[k]    = 0.0f;
    }

    __shared__ float red[4][N_OUT];      // per-wave partial sums (spike path)
    __shared__ float s_vout[N_OUT], s_iout[N_OUT], s_vmax[N_OUT];
    if (tid < N_OUT) {
        s_vout[tid] = 0.0f;
        s_iout[tid] = 0.0f;
        s_vmax[tid] = -INFINITY;
    }
    // (first __syncthreads_or below is a full barrier; readout LDS is only
    //  read/written by the same owning thread tid<10 until then)

    for (int t = 0; t < T_STEPS; ++t) {
        float s[N_OUT];
#pragma unroll
        for (int o = 0; o < N_OUT; ++o) s[o] = 0.0f;
        int any_spike = 0;

#pragma unroll
        for (int k = 0; k < NK; ++k) {
            // encoder LIF
            v_enc[k] += DT_TMI * (xk[k] - v_enc[k]);
            float z_enc = (v_enc[k] > V_TH) ? 1.0f : 0.0f;
            v_enc[k] = (v_enc[k] > V_TH) ? 0.0f : v_enc[k];
            // hidden LIF
            float v_dec = v0[k] + DT_TMI * (i0[k] - v0[k]);
            float i_dec = DEC_SYN * i0[k];
            bool  z0    = v_dec > V_TH;
            v0[k] = z0 ? 0.0f : v_dec;
            i0[k] = i_dec + z_enc;
            if (z0 && jn[k] < N_IN) {
                any_spike = 1;
#pragma unroll
                for (int o = 0; o < N_OUT; ++o)
                    s[o] += W[o * N_IN + jn[k]];   // L2-resident, spike-only
            }
        }

        const int any = __syncthreads_or(any_spike);

        if (any) {
            // wave-level reduction of s[10] (width 64)
#pragma unroll
            for (int o = 0; o < N_OUT; ++o) {
                float v = s[o];
                v += __shfl_down(v, 32, 64);
                v += __shfl_down(v, 16, 64);
                v += __shfl_down(v,  8, 64);
                v += __shfl_down(v,  4, 64);
                v += __shfl_down(v,  2, 64);
                v += __shfl_down(v,  1, 64);
                s[o] = v;
            }
            const int wave = tid >> 6;
            if ((tid & 63) == 0) {
#pragma unroll
                for (int o = 0; o < N_OUT; ++o) red[wave][o] = s[o];
            }
            __syncthreads();
        }

        if (tid < N_OUT) {
            float jump = s_iout[tid];
            if (any)
                jump += red[0][tid] + red[1][tid] + red[2][tid] + red[3][tid];
            float v = s_vout[tid] + DT_TMI * (jump - s_vout[tid]);
            s_vout[tid] = v;
            s_iout[tid] = DEC_SYN * jump;
            s_vmax[tid] = fmaxf(s_vmax[tid], v);
        }
        // no trailing barrier needed: next iteration's __syncthreads_or
        // separates this step's red[] reads from next step's red[] writes.
    }

    __syncthreads();
    if (tid == 0) {
        // log_softmax over 10 values (serial — trivial)
        float m = -INFINITY;
#pragma unroll
        for (int o = 0; o < N_OUT; ++o) m = fmaxf(m, s_vmax[o]);
        float sum = 0.0f;
#pragma unroll
        for (int o = 0; o < N_OUT; ++o) sum += expf(s_vmax[o] - m);
        const float lse = m + logf(sum);
        float* orow = out + (size_t)b * N_OUT;
#pragma unroll
        for (int o = 0; o < N_OUT; ++o) orow[o] = s_vmax[o] - lse;
    }
}

extern "C" void kernel_launch(void* const* d_in, const int* in_sizes, int n_in,
                              void* d_out, int out_size, void* d_ws, size_t ws_size,
                              hipStream_t stream) {
    const float* image = (const float*)d_in[0];   // [4096,1,28,28] fp32
    const float* W     = (const float*)d_in[1];   // [10,784] fp32
    float*       out   = (float*)d_out;           // [4096,10] fp32

    const int B = in_sizes[0] / N_IN;             // 4096
    snn_fused_kernel<<<B, 256, 0, stream>>>(image, W, out);
}

// Round 2
// 62.433 us; speedup vs baseline: 2.2495x; 2.2495x over previous
//
#include <hip/hip_runtime.h>
#include <math.h>

// SNN forward: ConstantCurrentLIFEncoder -> LIFCell -> LILinearCell, T=32.
// One block per batch item (B=4096), 256 threads, 4 neurons/thread.
//
// Event-driven shortcut (exact, not approximate): the encoder membrane obeys
// v' = 0.9 v + 0.1 x, a convex combination, so v stays <= max(v0, x) = x.
// A spike requires v > V_TH = 1.0 strictly; if every x in the batch row is
// <= 1.0 the encoder can NEVER spike (fp32 rounding of a convex combination
// cannot exceed the larger endpoint), so the hidden layer (zero-init) stays
// silent and v_out == 0 for all t  =>  output row is log_softmax(0) =
// -log(10), a constant. Blocks where any x > 1.0 run the full verified
// 32-step simulation (identical to the R1 kernel that passed with absmax 0).

#define T_STEPS 32
#define N_IN 784
#define N_OUT 10
#define NK 4            // neurons per thread (256*4 = 1024 >= 784)

__global__ __launch_bounds__(256) void snn_fused_kernel(
    const float* __restrict__ image,   // [B, 784]
    const float* __restrict__ W,       // [10, 784]
    float* __restrict__ out)           // [B, 10]
{
    constexpr float DT_TMI  = 0.1f;    // DT * TAU_MEM_INV
    constexpr float DEC_SYN = 0.8f;    // 1 - DT * TAU_SYN_INV
    constexpr float V_TH    = 1.0f;
    constexpr float NEG_LOG10 = -2.30258509299404568402f;  // log_softmax(0)_i

    const int b   = blockIdx.x;
    const int tid = threadIdx.x;
    const float* __restrict__ x_row = image + (size_t)b * N_IN;

    // load inputs + encoder-spike feasibility gate
    float xk[NK];
    int   jn[NK];
    int   can_spike = 0;
#pragma unroll
    for (int k = 0; k < NK; ++k) {
        int j = tid + 256 * k;
        jn[k] = j;
        xk[k] = (j < N_IN) ? x_row[j] : 0.0f;
        can_spike |= (xk[k] > V_TH);
    }

    if (!__syncthreads_or(can_spike)) {
        // No encoder spike possible anywhere in this batch row => exact
        // output is the constant log_softmax of the zero vector.
        if (tid < N_OUT) out[(size_t)b * N_OUT + tid] = NEG_LOG10;
        return;
    }

    // ---- rare path: full simulation (identical to verified R1 kernel) ----
    float v_enc[NK], v0[NK], i0[NK];
#pragma unroll
    for (int k = 0; k < NK; ++k) { v_enc[k] = 0.0f; v0[k] = 0.0f; i0[k] = 0.0f; }

    __shared__ float red[4][N_OUT];      // per-wave partial sums (spike path)
    __shared__ float s_vout[N_OUT], s_iout[N_OUT], s_vmax[N_OUT];
    if (tid < N_OUT) {
        s_vout[tid] = 0.0f;
        s_iout[tid] = 0.0f;
        s_vmax[tid] = -INFINITY;
    }

    for (int t = 0; t < T_STEPS; ++t) {
        float s[N_OUT];
#pragma unroll
        for (int o = 0; o < N_OUT; ++o) s[o] = 0.0f;
        int any_spike = 0;

#pragma unroll
        for (int k = 0; k < NK; ++k) {
            // encoder LIF
            v_enc[k] += DT_TMI * (xk[k] - v_enc[k]);
            float z_enc = (v_enc[k] > V_TH) ? 1.0f : 0.0f;
            v_enc[k] = (v_enc[k] > V_TH) ? 0.0f : v_enc[k];
            // hidden LIF
            float v_dec = v0[k] + DT_TMI * (i0[k] - v0[k]);
            float i_dec = DEC_SYN * i0[k];
            bool  z0    = v_dec > V_TH;
            v0[k] = z0 ? 0.0f : v_dec;
            i0[k] = i_dec + z_enc;
            if (z0 && jn[k] < N_IN) {
                any_spike = 1;
#pragma unroll
                for (int o = 0; o < N_OUT; ++o)
                    s[o] += W[o * N_IN + jn[k]];   // L2-resident, spike-only
            }
        }

        const int any = __syncthreads_or(any_spike);

        if (any) {
            // wave-level reduction of s[10] (width 64)
#pragma unroll
            for (int o = 0; o < N_OUT; ++o) {
                float v = s[o];
                v += __shfl_down(v, 32, 64);
                v += __shfl_down(v, 16, 64);
                v += __shfl_down(v,  8, 64);
                v += __shfl_down(v,  4, 64);
                v += __shfl_down(v,  2, 64);
                v += __shfl_down(v,  1, 64);
                s[o] = v;
            }
            const int wave = tid >> 6;
            if ((tid & 63) == 0) {
#pragma unroll
                for (int o = 0; o < N_OUT; ++o) red[wave][o] = s[o];
            }
            __syncthreads();
        }

        if (tid < N_OUT) {
            float jump = s_iout[tid];
            if (any)
                jump += red[0][tid] + red[1][tid] + red[2][tid] + red[3][tid];
            float v = s_vout[tid] + DT_TMI * (jump - s_vout[tid]);
            s_vout[tid] = v;
            s_iout[tid] = DEC_SYN * jump;
            s_vmax[tid] = fmaxf(s_vmax[tid], v);
        }
        // next iteration's __syncthreads_or separates red[] reads from writes
    }

    __syncthreads();
    if (tid == 0) {
        float m = -INFINITY;
#pragma unroll
        for (int o = 0; o < N_OUT; ++o) m = fmaxf(m, s_vmax[o]);
        float sum = 0.0f;
#pragma unroll
        for (int o = 0; o < N_OUT; ++o) sum += expf(s_vmax[o] - m);
        const float lse = m + logf(sum);
        float* orow = out + (size_t)b * N_OUT;
#pragma unroll
        for (int o = 0; o < N_OUT; ++o) orow[o] = s_vmax[o] - lse;
    }
}

extern "C" void kernel_launch(void* const* d_in, const int* in_sizes, int n_in,
                              void* d_out, int out_size, void* d_ws, size_t ws_size,
                              hipStream_t stream) {
    const float* image = (const float*)d_in[0];   // [4096,1,28,28] fp32
    const float* W     = (const float*)d_in[1];   // [10,784] fp32
    float*       out   = (float*)d_out;           // [4096,10] fp32

    const int B = in_sizes[0] / N_IN;             // 4096
    snn_fused_kernel<<<B, 256, 0, stream>>>(image, W, out);
}

// Round 3
// 61.094 us; speedup vs baseline: 2.2989x; 1.0219x over previous
//
#include <hip/hip_runtime.h>
#include <math.h>

// SNN forward: ConstantCurrentLIFEncoder -> LIFCell -> LILinearCell, T=32.
//
// One WAVE (64 lanes) per batch row; 4 waves/block; no __syncthreads at all.
// Each lane loads up to 4 float4 (row = 196 aligned float4s).
//
// Exact event-driven shortcut: encoder membrane obeys v' = 0.9 v + 0.1 x
// (convex combination => v <= x always, incl. fp32 rounding). Spike needs
// v > 1.0 strictly, so if all x <= 1.0 in the row, the encoder never fires,
// the hidden layer (zero-init) stays silent, v_out == 0 for all t, and the
// output row is the constant log_softmax(0) = -log(10). Rows failing the
// gate run a full 32-step simulation (state kept in d_ws global scratch so
// the rare path does not inflate the kernel's VGPR allocation).

#define N_IN   784
#define N_OUT  10
#define T_STEPS 32
#define ROW_F4 196          // float4s per row (784/4)
#define WS_ROW 2382         // floats of scratch per row: 3*784 states + 30 readout

__global__ __launch_bounds__(256) void snn_wave_kernel(
    const float* __restrict__ image,   // [B, 784]
    const float* __restrict__ W,       // [10, 784]
    float* __restrict__ out,           // [B, 10]
    float* __restrict__ ws,            // scratch (slow path only)
    int B)
{
    constexpr float DT_TMI  = 0.1f;    // DT * TAU_MEM_INV (exact fp32 match)
    constexpr float DEC_SYN = 0.8f;    // 1 - DT * TAU_SYN_INV
    constexpr float V_TH    = 1.0f;
    constexpr float NEG_LOG10 = -2.30258509299404568402f;

    const int wave = threadIdx.x >> 6;
    const int lane = threadIdx.x & 63;
    const int row  = blockIdx.x * 4 + wave;
    if (row >= B) return;                       // wave-uniform

    const float4* __restrict__ x4 = (const float4*)(image + (size_t)row * N_IN);

    // lane's chunks: lane, lane+64, lane+128, and (lane<4) lane+192
    const bool has4 = (lane < 4);
    float4 c0 = x4[lane];
    float4 c1 = x4[lane + 64];
    float4 c2 = x4[lane + 128];
    float4 c3 = has4 ? x4[lane + 192] : make_float4(0.f, 0.f, 0.f, 0.f);

    // gate: any x > V_TH anywhere in the row?
    float m = fmaxf(fmaxf(fmaxf(c0.x, c0.y), fmaxf(c0.z, c0.w)),
                    fmaxf(fmaxf(c1.x, c1.y), fmaxf(c1.z, c1.w)));
    m = fmaxf(m, fmaxf(fmaxf(c2.x, c2.y), fmaxf(c2.z, c2.w)));
    m = fmaxf(m, fmaxf(fmaxf(c3.x, c3.y), fmaxf(c3.z, c3.w)));

    if (!__any(m > V_TH)) {
        // Exact output: log_softmax of the all-zero v_max vector.
        if (lane < N_OUT) out[(size_t)row * N_OUT + lane] = NEG_LOG10;
        return;
    }

    // ---------------- rare path: full 32-step simulation ----------------
    // Neuron states live in global scratch (perf-irrelevant; never taken for
    // inputs in [0,1]). Layout per row: v_enc[784], v0[784], i0[784],
    // then readout: v_out[10], i_out[10], v_max[10].
    float* const rb   = ws + (size_t)row * WS_ROW;
    float* const p_ve = rb;
    float* const p_v0 = rb + N_IN;
    float* const p_i0 = rb + 2 * N_IN;
    float* const p_ro = rb + 3 * N_IN;          // 30 readout floats

    const float xv[16] = { c0.x, c0.y, c0.z, c0.w,  c1.x, c1.y, c1.z, c1.w,
                           c2.x, c2.y, c2.z, c2.w,  c3.x, c3.y, c3.z, c3.w };
    const int   cbase[4] = { lane, lane + 64, lane + 128, lane + 192 };
    const int   nch = has4 ? 4 : 3;

    // init states owned by this lane
    for (int c = 0; c < nch; ++c) {
        const int j0 = 4 * cbase[c];
#pragma unroll
        for (int e = 0; e < 4; ++e) {
            p_ve[j0 + e] = 0.0f; p_v0[j0 + e] = 0.0f; p_i0[j0 + e] = 0.0f;
        }
    }
    if (lane == 0) {
#pragma unroll
        for (int o = 0; o < N_OUT; ++o) {
            p_ro[o] = 0.0f;                     // v_out
            p_ro[10 + o] = 0.0f;                // i_out
            p_ro[20 + o] = -INFINITY;           // v_max
        }
    }
    // No cross-lane memory deps within a step: each lane touches only its own
    // neurons; readout is lane 0 only; spike sums travel via shuffles.

    for (int t = 0; t < T_STEPS; ++t) {
        float s[N_OUT];
#pragma unroll
        for (int o = 0; o < N_OUT; ++o) s[o] = 0.0f;

        for (int c = 0; c < nch; ++c) {
            const int j0 = 4 * cbase[c];
#pragma unroll
            for (int e = 0; e < 4; ++e) {
                const int j = j0 + e;
                const float x = xv[4 * c + e];
                float ve = p_ve[j], v0 = p_v0[j], i0 = p_i0[j];
                // encoder LIF
                ve += DT_TMI * (x - ve);
                const float z_enc = (ve > V_TH) ? 1.0f : 0.0f;
                ve = (ve > V_TH) ? 0.0f : ve;
                // hidden LIF
                const float v_dec = v0 + DT_TMI * (i0 - v0);
                const float i_dec = DEC_SYN * i0;
                const bool  z0    = v_dec > V_TH;
                p_ve[j] = ve;
                p_v0[j] = z0 ? 0.0f : v_dec;
                p_i0[j] = i_dec + z_enc;
                if (z0) {
#pragma unroll
                    for (int o = 0; o < N_OUT; ++o) s[o] += W[o * N_IN + j];
                }
            }
        }

        // wave-reduce the 10 spike-weight sums to lane 0
#pragma unroll
        for (int o = 0; o < N_OUT; ++o) {
            float v = s[o];
            v += __shfl_down(v, 32, 64);
            v += __shfl_down(v, 16, 64);
            v += __shfl_down(v,  8, 64);
            v += __shfl_down(v,  4, 64);
            v += __shfl_down(v,  2, 64);
            v += __shfl_down(v,  1, 64);
            s[o] = v;
        }

        if (lane == 0) {
#pragma unroll
            for (int o = 0; o < N_OUT; ++o) {
                const float jump = p_ro[10 + o] + s[o];
                const float v    = p_ro[o] + DT_TMI * (jump - p_ro[o]);
                p_ro[o]      = v;
                p_ro[10 + o] = DEC_SYN * jump;
                p_ro[20 + o] = fmaxf(p_ro[20 + o], v);
            }
        }
    }

    if (lane == 0) {
        float mm = -INFINITY;
#pragma unroll
        for (int o = 0; o < N_OUT; ++o) mm = fmaxf(mm, p_ro[20 + o]);
        float sum = 0.0f;
#pragma unroll
        for (int o = 0; o < N_OUT; ++o) sum += expf(p_ro[20 + o] - mm);
        const float lse = mm + logf(sum);
        float* orow = out + (size_t)row * N_OUT;
#pragma unroll
        for (int o = 0; o < N_OUT; ++o) orow[o] = p_ro[20 + o] - lse;
    }
}

extern "C" void kernel_launch(void* const* d_in, const int* in_sizes, int n_in,
                              void* d_out, int out_size, void* d_ws, size_t ws_size,
                              hipStream_t stream) {
    const float* image = (const float*)d_in[0];   // [4096,1,28,28] fp32
    const float* W     = (const float*)d_in[1];   // [10,784] fp32
    float*       out   = (float*)d_out;           // [4096,10] fp32

    const int B = in_sizes[0] / N_IN;             // 4096
    const int blocks = (B + 3) / 4;               // one wave per row
    snn_wave_kernel<<<blocks, 256, 0, stream>>>(image, W, out, (float*)d_ws, B);
}